// Round 3
// baseline (63.088 us; speedup 1.0000x reference)
//
#include <hip/hip_runtime.h>

#define FLOOR_EPS 1e-6f

// Problem shape (from reference): B=32, C=1, F=128, T=8000
constexpr int Bq = 32, Cq = 1, Fq = 128, Tq = 8000;
constexpr int ROWS = Bq * Cq * Fq;            // 4096 independent rows
constexpr int LPR  = 8;                       // elems per lane per round (2 float4)
constexpr int RNDE = 64 * LPR;                // 512 elems per round per wave
constexpr int NR   = (Tq + RNDE - 1) / RNDE;  // 16 rounds (round 15 partial: 320 els)
constexpr int LACT = (Tq - (NR - 1) * RNDE) / LPR; // 40 active lanes in last round
constexpr int WPB  = 4;                       // waves (=rows) per block

__global__ __launch_bounds__(256, 4)
void _PCEN_75033078661345_kernel(const float* __restrict__ x,
                                 const float* __restrict__ alpha,
                                 const float* __restrict__ delta,
                                 const float* __restrict__ root,
                                 const float* __restrict__ smooth,
                                 float* __restrict__ out,   // ROWS*T
                                 float* __restrict__ hid)   // ROWS
{
    const int lane = threadIdx.x & 63;
    const int wid  = threadIdx.x >> 6;
    const int r    = blockIdx.x * WPB + wid;   // one wave per row, no block sync
    const int c    = (r / Fq) % Cq;

    const float w   = fminf(fmaxf(smooth[0], 0.f), 1.f);
    const float om  = 1.f - w;
    const float aa  = fminf(alpha[c], 1.f);
    const float dd  = delta[c];
    const float oor = 1.f / fmaxf(root[c], 1.f);
    const bool  us  = (oor == 0.5f);
    const float droot = us ? __builtin_amdgcn_sqrtf(dd)
                           : __builtin_amdgcn_exp2f(oor * __builtin_amdgcn_logf(dd));

    // omp[k] = om^(8 * 2^k)  via repeated squaring (no log of om: safe at om=0)
    float om2 = om * om, om4 = om2 * om2;
    float omp[6];
    omp[0] = om4 * om4;
    #pragma unroll
    for (int k = 1; k < 6; ++k) omp[k] = omp[k - 1] * omp[k - 1];
    // om8i = om^(8*lane): select-by-bit products (static, 6 mul+cndmask)
    float om8i = 1.f;
    #pragma unroll
    for (int k = 0; k < 6; ++k) om8i = ((lane >> k) & 1) ? om8i * omp[k] : om8i;
    const float omR = omp[5] * omp[5];         // om^512 (per-round carry decay)

    const float* row  = x   + (size_t)r * Tq;
    float*       orow = out + (size_t)r * Tq;

    float carry = row[0];                      // EMA state before t=0 (init = x[0])

    // triple-buffer prefetch, fully unrolled -> all indices static (no scratch)
    float4 buf[3][2];
    #pragma unroll
    for (int s = 0; s < 2; ++s) {              // rounds 0,1 are full rounds (NR=16)
        const float4* p = (const float4*)(row + s * RNDE + lane * LPR);
        buf[s][0] = p[0]; buf[s][1] = p[1];
    }

    float accL = 0.f;
    #pragma unroll
    for (int s = 0; s < NR; ++s) {
        // ---- prefetch round s+2 (coalesced: lane i at i*32B) ----
        if (s + 2 < NR) {
            const bool pact = (s + 2 < NR - 1) || (lane < LACT);
            float4 n0 = {0,0,0,0}, n1 = {0,0,0,0};
            if (pact) {
                const float4* p = (const float4*)(row + (s + 2) * RNDE + lane * LPR);
                n0 = p[0]; n1 = p[1];
            }
            buf[(s + 2) % 3][0] = n0; buf[(s + 2) % 3][1] = n1;
        }

        const float4 c0 = buf[s % 3][0], c1 = buf[s % 3][1];
        const float xv[LPR] = {c0.x, c0.y, c0.z, c0.w, c1.x, c1.y, c1.z, c1.w};

        // ---- local affine offset over 8 elems (coefficient om^8 is constant) ----
        float b = 0.f;
        #pragma unroll
        for (int j = 0; j < LPR; ++j) b = w * xv[j] + om * b;

        // ---- Kogge-Stone scan, constant coefficient: 6 shuffles, 1 value ----
        #pragma unroll
        for (int k = 0; k < 6; ++k) {
            const float pb = __shfl_up(b, 1 << k);
            const float nb = fmaf(omp[k], pb, b);
            b = (lane >= (1 << k)) ? nb : b;
        }
        const float pb1 = __shfl_up(b, 1);
        const float bex = (lane == 0) ? 0.f : pb1;          // exclusive prefix
        float acc = fmaf(om8i, carry, bex);                 // EMA state entering lane
        const float btot = __shfl(b, 63);
        carry = fmaf(omR, carry, btot);                     // state after this round

        // ---- pointwise PCEN + coalesced store ----
        float ov[LPR];
        #pragma unroll
        for (int j = 0; j < LPR; ++j) {
            acc = w * xv[j] + om * acc;                     // exact sequential EMA
            const float dp = __builtin_amdgcn_exp2f(-aa * __builtin_amdgcn_logf(FLOOR_EPS + acc));
            const float tt = fmaf(xv[j], dp, dd);
            ov[j] = us ? (__builtin_amdgcn_sqrtf(tt) - droot)
                       : (__builtin_amdgcn_exp2f(oor * __builtin_amdgcn_logf(tt)) - droot);
        }
        const bool act = (s < NR - 1) || (lane < LACT);
        if (act) {
            float4* q = (float4*)(orow + s * RNDE + lane * LPR);
            float4 o0 = {ov[0], ov[1], ov[2], ov[3]};
            float4 o1 = {ov[4], ov[5], ov[6], ov[7]};
            q[0] = o0; q[1] = o1;
        }
        accL = acc;
    }

    // hidden state = final EMA (lane LACT-1 of last round holds ema[T-1])
    const float h = __shfl(accL, LACT - 1);
    if (lane == 0) hid[r] = h;
}

extern "C" void kernel_launch(void* const* d_in, const int* in_sizes, int n_in,
                              void* d_out, int out_size, void* d_ws, size_t ws_size,
                              hipStream_t stream) {
    const float* x      = (const float*)d_in[0];
    const float* alpha  = (const float*)d_in[1];
    const float* delta  = (const float*)d_in[2];
    const float* root   = (const float*)d_in[3];
    const float* smooth = (const float*)d_in[4];
    float* out = (float*)d_out;
    float* hid = out + (size_t)ROWS * Tq;

    _PCEN_75033078661345_kernel<<<ROWS / WPB, 256, 0, stream>>>(
        x, alpha, delta, root, smooth, out, hid);
}

// Round 4
// 53.261 us; speedup vs baseline: 1.1845x; 1.1845x over previous
//
#include <hip/hip_runtime.h>

#define FLOOR_EPS 1e-6f

// Problem shape (from reference): B=32, C=1, F=128, T=8000
constexpr int Bq = 32, Cq = 1, Fq = 128, Tq = 8000;
constexpr int ROWS  = Bq * Cq * Fq;             // 4096 independent rows
constexpr int LPR   = 8;                        // elems per lane per round
constexpr int RNDE  = 64 * LPR;                 // 512 elems per round per wave
constexpr int SPLIT = 2;                        // waves per row (temporal split)
constexpr int MAIN  = Tq / SPLIT;               // 4000 elems per wave's own region
constexpr int NRM   = (MAIN + RNDE - 1) / RNDE; // 8 main rounds (last partial)
constexpr int LACT  = (MAIN - (NRM - 1) * RNDE) / LPR; // 52 active lanes, last round
constexpr int WPB   = 4;                        // waves per block
constexpr unsigned TOTE = (unsigned)ROWS * Tq;  // total elements (fits 32-bit)

__global__ __launch_bounds__(256)
void _PCEN_75033078661345_kernel(const float* __restrict__ x,
                                 const float* __restrict__ alpha,
                                 const float* __restrict__ delta,
                                 const float* __restrict__ root,
                                 const float* __restrict__ smooth,
                                 float* __restrict__ out,   // ROWS*T
                                 float* __restrict__ hid)   // ROWS
{
    const int lane = threadIdx.x & 63;
    const int wid  = threadIdx.x >> 6;
    const int gw   = blockIdx.x * WPB + wid;   // global wave id, 0..ROWS*SPLIT-1
    const int r    = gw >> 1;                  // row
    const int h    = gw & 1;                   // which half of the row
    const int c    = (r / Fq) % Cq;

    const float w   = fminf(fmaxf(smooth[0], 0.f), 1.f);
    const float om  = 1.f - w;
    const float aa  = fminf(alpha[c], 1.f);
    const float dd  = delta[c];
    const float oor = 1.f / fmaxf(root[c], 1.f);
    const bool  us  = (oor == 0.5f);
    const float droot = us ? __builtin_amdgcn_sqrtf(dd)
                           : __builtin_amdgcn_exp2f(oor * __builtin_amdgcn_logf(dd));

    // omp[k] = om^(8 * 2^k) by squaring; om8i = om^(8*lane); omR = om^512
    float om2 = om * om, om4 = om2 * om2;
    float omp[6];
    omp[0] = om4 * om4;
    #pragma unroll
    for (int k = 1; k < 6; ++k) omp[k] = omp[k - 1] * omp[k - 1];
    float om8i = 1.f;
    #pragma unroll
    for (int k = 0; k < 6; ++k) om8i = ((lane >> k) & 1) ? om8i * omp[k] : om8i;
    const float omR = omp[5] * omp[5];

    // Warmup rounds for h=1: window W=Rw*512 with om^W <= ~2^-30 (runtime-adaptive).
    int Rw = 0;
    if (h) {
        const float nl2 = fmaxf(-__builtin_amdgcn_logf(om), 1e-9f); // -log2(om)
        float need = 30.f / (512.f * nl2);
        int ri = (int)ceilf(need);
        Rw = ri < 1 ? 1 : (ri > 7 ? 7 : ri);   // cap: w0 stays >= 0
    }
    const int w0 = h * MAIN - Rw * RNDE;       // first round's base element in row
    const int nr = NRM + Rw;                   // total rounds this wave

    const unsigned rowbase = (unsigned)r * (unsigned)Tq;

    // EMA state entering element w0: exact init x[0] for h=0; windowed seed else.
    float carry = x[rowbase + (unsigned)w0];
    float accv  = 0.f;

    auto LOADR = [&](int sidx, float4& d0, float4& d1) {
        unsigned u = rowbase + (unsigned)(w0 + sidx * RNDE + lane * LPR);
        u = u > (TOTE - LPR) ? (TOTE - LPR) : u;   // clamp only matters at buffer end
        const float4* p = (const float4*)(x + u);
        d0 = p[0]; d1 = p[1];
    };

    auto ROUND = [&](int sidx, float4 c0, float4 c1) {
        const float xv[LPR] = {c0.x, c0.y, c0.z, c0.w, c1.x, c1.y, c1.z, c1.w};
        // local affine offset over 8 elems (coefficient om^8 uniform)
        float b = 0.f;
        #pragma unroll
        for (int j = 0; j < LPR; ++j) b = w * xv[j] + om * b;
        // Kogge-Stone scan with constant per-level coefficient: 6 shuffles
        #pragma unroll
        for (int k = 0; k < 6; ++k) {
            const float pb = __shfl_up(b, 1 << k);
            const float nb = fmaf(omp[k], pb, b);
            b = (lane >= (1 << k)) ? nb : b;
        }
        const float pb1  = __shfl_up(b, 1);
        const float bex  = (lane == 0) ? 0.f : pb1;
        float acc        = fmaf(om8i, carry, bex);   // state entering this lane
        const float btot = __shfl(b, 63);
        carry = fmaf(omR, carry, btot);              // state after this round
        if (sidx >= Rw) {                            // main region: pointwise + store
            float ov[LPR];
            #pragma unroll
            for (int j = 0; j < LPR; ++j) {
                acc = w * xv[j] + om * acc;          // exact sequential EMA
                const float dp = __builtin_amdgcn_exp2f(-aa * __builtin_amdgcn_logf(FLOOR_EPS + acc));
                const float tt = fmaf(xv[j], dp, dd);
                ov[j] = us ? (__builtin_amdgcn_sqrtf(tt) - droot)
                           : (__builtin_amdgcn_exp2f(oor * __builtin_amdgcn_logf(tt)) - droot);
            }
            const bool lastr = (sidx == nr - 1);
            if (!lastr || lane < LACT) {
                float4* q = (float4*)(out + rowbase + (unsigned)(w0 + sidx * RNDE + lane * LPR));
                float4 o0 = {ov[0], ov[1], ov[2], ov[3]};
                float4 o1 = {ov[4], ov[5], ov[6], ov[7]};
                q[0] = o0; q[1] = o1;
            }
            accv = acc;
        }
    };

    // ---- software pipeline: 2-deep prefetch, manually 2x unrolled (static regs)
    float4 A0, A1, B0, B1;
    LOADR(0, A0, A1);
    LOADR(1, B0, B1);
    int s = 0;
    for (; s + 1 < nr; s += 2) {
        float4 c0 = A0, c1 = A1;
        if (s + 2 < nr) LOADR(s + 2, A0, A1);
        ROUND(s, c0, c1);
        c0 = B0; c1 = B1;
        if (s + 3 < nr) LOADR(s + 3, B0, B1);
        ROUND(s + 1, c0, c1);
    }
    if (s < nr) ROUND(s, A0, A1);

    // hidden state = final EMA of the row, owned by the h=1 wave's last round
    const float hh = __shfl(accv, LACT - 1);
    if (h == 1 && lane == 0) hid[r] = hh;
}

extern "C" void kernel_launch(void* const* d_in, const int* in_sizes, int n_in,
                              void* d_out, int out_size, void* d_ws, size_t ws_size,
                              hipStream_t stream) {
    const float* x      = (const float*)d_in[0];
    const float* alpha  = (const float*)d_in[1];
    const float* delta  = (const float*)d_in[2];
    const float* root   = (const float*)d_in[3];
    const float* smooth = (const float*)d_in[4];
    float* out = (float*)d_out;
    float* hid = out + (size_t)ROWS * Tq;

    _PCEN_75033078661345_kernel<<<(ROWS * SPLIT) / WPB, 256, 0, stream>>>(
        x, alpha, delta, root, smooth, out, hid);
}